// Round 9
// baseline (369.835 us; speedup 1.0000x reference)
//
#include <hip/hip_runtime.h>
#include <hip/hip_bf16.h>

#define N_NODES 100000
#define N_EDGES 800000
#define D 128
#define NH 8
#define NB ((N_NODES + 255) / 256)   // 391 blocks (prep zero / scan_one)
#define NBQ ((N_NODES + 63) / 64)    // 1563 qkv blocks (64 rows each)

typedef __hip_bfloat16 bf16;
typedef __bf16 bf16x8 __attribute__((ext_vector_type(8)));
typedef float  f32x4  __attribute__((ext_vector_type(4)));

__device__ __forceinline__ unsigned short f2bu(float x) {
    bf16 b = __float2bfloat16(x);
    return *reinterpret_cast<unsigned short*>(&b);
}
__device__ __forceinline__ float bu2f(unsigned short u) {
    return __uint_as_float(((unsigned)u) << 16);
}
__device__ __forceinline__ float bfe0(unsigned u) { return __uint_as_float(u << 16); }
__device__ __forceinline__ float bfe1(unsigned u) { return __uint_as_float(u & 0xffff0000u); }

union frag_u { unsigned short u[8]; bf16x8 v; };

// DPP-based add of a lane-shuffled copy (VALU pipe; no DS traffic).
template<int CTRL>
__device__ __forceinline__ float dpp_add(float x) {
    int y = __builtin_amdgcn_mov_dpp(__float_as_int(x), CTRL, 0xf, 0xf, true);
    return x + __int_as_float(y);
}
// Sum over each aligned 8-lane group: xor1, xor2, xor7 spans the 3-bit group.
__device__ __forceinline__ float red8(float x) {
    x = dpp_add<0xB1>(x);    // quad_perm [1,0,3,2]  -> lane ^ 1
    x = dpp_add<0x4E>(x);    // quad_perm [2,3,0,1]  -> lane ^ 2
    x = dpp_add<0x141>(x);   // row_half_mirror      -> lane ^ 7
    return x;
}

// ---------------------------------------------------------------------------
// Kernel 0: lay W out in MFMA B-fragment order (hi/lo bf16 split), zero the
// per-node edge counters and the global scan cursor.
// Matrix 0 = Q.  Matrices 1,2 = KV-low/KV-high with columns permuted so the
// MFMA output row IS the fused dword-interleaved KV layout.
// ---------------------------------------------------------------------------
__global__ __launch_bounds__(256) void prep_kernel(
    const float* __restrict__ Wq, const float* __restrict__ Wk, const float* __restrict__ Wv,
    unsigned short* __restrict__ Wf, int* __restrict__ counts, int* __restrict__ gcur)
{
    int t = blockIdx.x * 256 + threadIdx.x;
    if (t < N_NODES) counts[t] = 0;
    if (t == 0) *gcur = 0;
    if (t < 3 * 32 * 64) {
        int lane = t & 63;
        int ct   = (t >> 6) & 31;
        int mat  = t >> 11;
        int c  = ct >> 3, tt = ct & 7;
        int n  = tt * 16 + (lane & 15);
        int kb = c * 32 + (lane >> 4) * 8;
        const float* W;
        int col;
        if (mat == 0) {
            W = Wq; col = n;
        } else {
            int g = (mat - 1) * 128 + n;
            W = (g & 2) ? Wv : Wk;
            col = ((g >> 2) << 1) | (g & 1);
        }
        unsigned short* dst = Wf + (size_t)mat * 32768 + (size_t)ct * 1024 + (size_t)lane * 8;
#pragma unroll
        for (int j = 0; j < 8; ++j) {
            float w  = W[(size_t)(kb + j) * D + col];
            unsigned short hb = f2bu(w);
            float lo = w - bu2f(hb);
            dst[j]       = hb;          // hi (part 0)
            dst[512 + j] = f2bu(lo);    // lo (part 1)
        }
    }
}

// ---------------------------------------------------------------------------
// Kernel 1: fused Q/KV projection via bf16 MFMA with hi/lo precision split.
// 64 rows/block, 16 rows/wave.  Edge histogram + rank capture fused into the
// prologue (makes scatter atomic-free).
// THIS ROUND: 1-phase register prefetch (issue-early/write-late) — each
// staging phase's 8 dwordx4 L2 loads are issued during the PREVIOUS phase's
// MFMA window, so the ~250-cycle L2 latency hides under compute instead of
// sitting naked between barriers.  Phases flat-indexed ph = mat*2 + half;
// phase ph stages Wf[ph*16384 .. +16384).
// ---------------------------------------------------------------------------
__global__ __launch_bounds__(256) void qkv_mfma(
    const float* __restrict__ E, const unsigned short* __restrict__ Wf,
    bf16* __restrict__ Q, char* __restrict__ KVb,
    const int* __restrict__ rows, int* __restrict__ counts,
    int* __restrict__ rank)
{
    __shared__ unsigned short bsh[16384];   // 32 KB: B staging, then epilogue
    const int tid  = threadIdx.x;
    const int wave = tid >> 6;
    const int lane = tid & 63;
    const int r0w  = blockIdx.x * 64 + wave * 16;   // this wave's 16 rows

    // --- edge histogram + rank capture: 2 edges/thread ---
    {
        int e0 = (blockIdx.x * 256 + tid) * 2;
        if (e0 < N_EDGES) {
            int2 r2 = *reinterpret_cast<const int2*>(rows + e0);
            int2 rk;
            rk.x = atomicAdd(&counts[r2.x], 1);
            rk.y = atomicAdd(&counts[r2.y], 1);
            *reinterpret_cast<int2*>(rank + e0) = rk;
        }
    }

    // --- prefetch phase 0's 32 KB into registers (completes under A-load) ---
    uint4 pre[8];
    {
        const uint4* s0 = reinterpret_cast<const uint4*>(Wf);
#pragma unroll
        for (int k = 0; k < 8; ++k)
            pre[k] = s0[k * 256 + tid];
    }

    const int am = lane & 15;    // A row within 16-tile
    const int aq = lane >> 4;    // k quad

    // Load + split A fragments: 4 k-chunks x 8 bf16 (hi/lo).
    frag_u ahi[4], alo[4];
    {
        int row = r0w + am;
        if (row >= N_NODES) row = N_NODES - 1;     // clamp; stores are guarded
        const float* erow = E + (size_t)row * D + aq * 8;
#pragma unroll
        for (int c = 0; c < 4; ++c) {
            float4 e0 = *reinterpret_cast<const float4*>(erow + c * 32);
            float4 e1 = *reinterpret_cast<const float4*>(erow + c * 32 + 4);
            float ef[8] = {e0.x, e0.y, e0.z, e0.w, e1.x, e1.y, e1.z, e1.w};
#pragma unroll
            for (int j = 0; j < 8; ++j) {
                unsigned short hb = f2bu(ef[j]);
                ahi[c].u[j] = hb;
                alo[c].u[j] = f2bu(ef[j] - bu2f(hb));
            }
        }
    }

#pragma unroll
    for (int mat = 0; mat < 3; ++mat) {
        f32x4 acc[8];
#pragma unroll
        for (int t = 0; t < 8; ++t)
            acc[t] = (f32x4){0.f, 0.f, 0.f, 0.f};

#pragma unroll
        for (int half = 0; half < 2; ++half) {
            const int ph = mat * 2 + half;
            __syncthreads();    // previous users of bsh are done
            // write-late: commit the prefetched 32 KB to LDS
            {
                uint4* dstv = reinterpret_cast<uint4*>(bsh);
#pragma unroll
                for (int k = 0; k < 8; ++k)
                    dstv[k * 256 + tid] = pre[k];
            }
            // issue-early: kick off next phase's loads; they fly during MFMA
            if (ph < 5) {
                const uint4* sn = reinterpret_cast<const uint4*>(Wf + (size_t)(ph + 1) * 16384);
#pragma unroll
                for (int k = 0; k < 8; ++k)
                    pre[k] = sn[k * 256 + tid];
            }
            __syncthreads();

#pragma unroll
            for (int t = 0; t < 8; ++t) {
#pragma unroll
                for (int cc = 0; cc < 2; ++cc) {
                    const unsigned short* bp = bsh + (cc * 8 + t) * 1024 + lane * 8;
                    bf16x8 bhi = *reinterpret_cast<const bf16x8*>(bp);
                    bf16x8 blo = *reinterpret_cast<const bf16x8*>(bp + 512);
                    const int c = half * 2 + cc;
                    acc[t] = __builtin_amdgcn_mfma_f32_16x16x32_bf16(alo[c].v, bhi, acc[t], 0, 0, 0);
                    acc[t] = __builtin_amdgcn_mfma_f32_16x16x32_bf16(ahi[c].v, blo, acc[t], 0, 0, 0);
                    acc[t] = __builtin_amdgcn_mfma_f32_16x16x32_bf16(ahi[c].v, bhi, acc[t], 0, 0, 0);
                }
            }
        }
        __syncthreads();   // all waves done reading B; bsh reusable per-wave

        // Epilogue: C-frags -> per-wave LDS slice (stride 136) -> coalesced
        // dwordx4 stores.  C layout: col = t*16+am, row = aq*4+r.
        unsigned short* ob = bsh + wave * 2176;   // 16 rows x 136
#pragma unroll
        for (int t = 0; t < 8; ++t)
#pragma unroll
            for (int r = 0; r < 4; ++r)
                ob[(aq * 4 + r) * 136 + t * 16 + am] = f2bu(acc[t][r]);
        {
            const int row = lane >> 2, c4 = lane & 3;
            int grow = r0w + row;
            if (grow < N_NODES) {
                const uint4* srcb = reinterpret_cast<const uint4*>(ob + row * 136 + c4 * 32);
                uint4 d0 = srcb[0], d1 = srcb[1], d2 = srcb[2], d3 = srcb[3];
                uint4* dst;
                if (mat == 0)
                    dst = reinterpret_cast<uint4*>(Q + (size_t)grow * D + c4 * 32);
                else
                    dst = reinterpret_cast<uint4*>(KVb + ((size_t)grow << 9)
                                                   + (size_t)(mat - 1) * 256 + (size_t)c4 * 64);
                dst[0] = d0; dst[1] = d1; dst[2] = d2; dst[3] = d3;
            }
        }
    }
}

// ---------------------------------------------------------------------------
// One-pass order-free exclusive offsets: wave prefix sum over 64 counts +
// one atomicAdd per wave on a global cursor.
// ---------------------------------------------------------------------------
__global__ __launch_bounds__(256) void scan_one(
    const int* __restrict__ counts, int* __restrict__ offsets,
    int* __restrict__ gcur)
{
    int lane = threadIdx.x & 63;
    int n = blockIdx.x * 256 + threadIdx.x;
    int v = (n < N_NODES) ? counts[n] : 0;
    int s = v;
#pragma unroll
    for (int d = 1; d < 64; d <<= 1) {
        int t = __shfl_up(s, d, 64);
        if (lane >= d) s += t;
    }
    int tot = __shfl(s, 63, 64);
    int base = 0;
    if (lane == 0) base = atomicAdd(gcur, tot);
    base = __shfl(base, 0, 64);
    if (n < N_NODES) offsets[n] = base + s - v;
}

// ---------------------------------------------------------------------------
// Atomic-free scatter: position = offsets[row] + rank[e] (rank captured by
// qkv's histogram).  4 edges/thread via int4 loads; N_EDGES % 4 == 0.
// ---------------------------------------------------------------------------
__global__ __launch_bounds__(256) void scatter_kernel(
    const int* __restrict__ rows, const int* __restrict__ cols,
    const int* __restrict__ rank, const int* __restrict__ offsets,
    int* __restrict__ csr_cols)
{
    int e0 = (blockIdx.x * 256 + threadIdx.x) * 4;
    if (e0 >= N_EDGES) return;
    int4 r4 = *reinterpret_cast<const int4*>(rows + e0);
    int4 k4 = *reinterpret_cast<const int4*>(rank + e0);
    int4 c4 = *reinterpret_cast<const int4*>(cols + e0);
    csr_cols[offsets[r4.x] + k4.x] = c4.x;
    csr_cols[offsets[r4.y] + k4.y] = c4.y;
    csr_cols[offsets[r4.z] + k4.z] = c4.z;
    csr_cols[offsets[r4.w] + k4.w] = c4.w;
}

// ---------------------------------------------------------------------------
// Fused per-node attention + residual + LayerNorm. One wave per node.
// (unchanged — pinned at ~76 µs by the random-gather LLC/HBM mix; every
// issue-rate improvement from rounds 0-4 moved it <6%, so traffic, not
// instructions, is the wall)
// ---------------------------------------------------------------------------
__device__ __forceinline__ void edge_body(
    const char* __restrict__ KVb, int off, unsigned lane8,
    float q0, float q1, float CLIP2,
    float& acc0, float& acc1, float& nrm)
{
    uint2 kv = *reinterpret_cast<const uint2*>(KVb + (unsigned)off + lane8);
    float p = q0 * bfe0(kv.x) + q1 * bfe1(kv.x);
    p = red8(p);
    float s = __builtin_amdgcn_exp2f(fminf(fmaxf(p, -CLIP2), CLIP2));
    nrm  += s;
    acc0 += s * bfe0(kv.y);
    acc1 += s * bfe1(kv.y);
}

__global__ __launch_bounds__(256) void fused_node(
    const bf16* __restrict__ Qb, const char* __restrict__ KVb,
    const int* __restrict__ offsets, const int* __restrict__ counts,
    const int* __restrict__ csr_cols,
    const float* __restrict__ emb,
    const float* __restrict__ gamma, const float* __restrict__ beta,
    float* __restrict__ out)
{
    int n = blockIdx.x * 4 + (threadIdx.x >> 6);     // grid covers exactly N_NODES
    int lane = threadIdx.x & 63;

    const float L2E   = 1.44269504f;
    const float CLIP2 = 14.4269504f;                 // 10 * log2(e)

    unsigned qu = *reinterpret_cast<const unsigned*>(Qb + (size_t)n * D + lane * 2);
    float q0 = bfe0(qu) * L2E, q1 = bfe1(qu) * L2E;

    int start = offsets[n];
    int cnt   = counts[n];
    unsigned lane8 = (unsigned)(lane << 3);

    float acc0a = 0.f, acc1a = 0.f, nrma = 0.f;
    float acc0b = 0.f, acc1b = 0.f, nrmb = 0.f;

    for (int base = 0; base < cnt; base += 64) {
        int m = cnt - base; if (m > 64) m = 64;
        int moff = (base + lane < cnt) ? (csr_cols[start + base + lane] << 9) : 0;
        int j = 0;
        for (; j + 7 < m; j += 8) {
            int o0 = __builtin_amdgcn_readlane(moff, j + 0);
            int o1 = __builtin_amdgcn_readlane(moff, j + 1);
            int o2 = __builtin_amdgcn_readlane(moff, j + 2);
            int o3 = __builtin_amdgcn_readlane(moff, j + 3);
            int o4 = __builtin_amdgcn_readlane(moff, j + 4);
            int o5 = __builtin_amdgcn_readlane(moff, j + 5);
            int o6 = __builtin_amdgcn_readlane(moff, j + 6);
            int o7 = __builtin_amdgcn_readlane(moff, j + 7);
            edge_body(KVb, o0, lane8, q0, q1, CLIP2, acc0a, acc1a, nrma);
            edge_body(KVb, o1, lane8, q0, q1, CLIP2, acc0b, acc1b, nrmb);
            edge_body(KVb, o2, lane8, q0, q1, CLIP2, acc0a, acc1a, nrma);
            edge_body(KVb, o3, lane8, q0, q1, CLIP2, acc0b, acc1b, nrmb);
            edge_body(KVb, o4, lane8, q0, q1, CLIP2, acc0a, acc1a, nrma);
            edge_body(KVb, o5, lane8, q0, q1, CLIP2, acc0b, acc1b, nrmb);
            edge_body(KVb, o6, lane8, q0, q1, CLIP2, acc0a, acc1a, nrma);
            edge_body(KVb, o7, lane8, q0, q1, CLIP2, acc0b, acc1b, nrmb);
        }
        for (; j + 3 < m; j += 4) {
            int o0 = __builtin_amdgcn_readlane(moff, j + 0);
            int o1 = __builtin_amdgcn_readlane(moff, j + 1);
            int o2 = __builtin_amdgcn_readlane(moff, j + 2);
            int o3 = __builtin_amdgcn_readlane(moff, j + 3);
            edge_body(KVb, o0, lane8, q0, q1, CLIP2, acc0a, acc1a, nrma);
            edge_body(KVb, o1, lane8, q0, q1, CLIP2, acc0b, acc1b, nrmb);
            edge_body(KVb, o2, lane8, q0, q1, CLIP2, acc0a, acc1a, nrma);
            edge_body(KVb, o3, lane8, q0, q1, CLIP2, acc0b, acc1b, nrmb);
        }
        for (; j < m; ++j) {
            int o0 = __builtin_amdgcn_readlane(moff, j);
            edge_body(KVb, o0, lane8, q0, q1, CLIP2, acc0a, acc1a, nrma);
        }
    }

    float nrm  = nrma + nrmb;
    float acc0 = acc0a + acc0b;
    float acc1 = acc1a + acc1b;

    float w = 1.f / (nrm + 1e-8f);
    float2 e2 = *reinterpret_cast<const float2*>(emb + (size_t)n * D + lane * 2);
    float x0 = acc0 * w + e2.x;
    float x1 = acc1 * w + e2.y;

    // single-pass LayerNorm: reduce sum and sumsq together
    float s1 = x0 + x1;
    float s2 = x0 * x0 + x1 * x1;
#pragma unroll
    for (int off = 32; off; off >>= 1) {
        s1 += __shfl_xor(s1, off, 64);
        s2 += __shfl_xor(s2, off, 64);
    }
    float mean = s1 * (1.0f / 128.0f);
    float var  = fmaxf(s2 * (1.0f / 128.0f) - mean * mean, 0.f);
    float rs = rsqrtf(var + 1e-6f);

    float d0 = x0 - mean, d1 = x1 - mean;
    float2 g2 = *reinterpret_cast<const float2*>(gamma + lane * 2);
    float2 b2 = *reinterpret_cast<const float2*>(beta + lane * 2);
    float2 o2 = make_float2(d0 * rs * g2.x + b2.x, d1 * rs * g2.y + b2.y);
    *reinterpret_cast<float2*>(out + (size_t)n * D + lane * 2) = o2;
}

// ---------------------------------------------------------------------------
extern "C" void kernel_launch(void* const* d_in, const int* in_sizes, int n_in,
                              void* d_out, int out_size, void* d_ws, size_t ws_size,
                              hipStream_t stream)
{
    const float* emb   = (const float*)d_in[0];
    const float* qW    = (const float*)d_in[1];
    const float* kW    = (const float*)d_in[2];
    const float* vW    = (const float*)d_in[3];
    const float* gamma = (const float*)d_in[4];
    const float* beta  = (const float*)d_in[5];
    const int*   eidx  = (const int*)d_in[6];
    const int*   rows  = eidx;
    const int*   cols  = eidx + N_EDGES;
    float* out = (float*)d_out;

    const size_t ND = (size_t)N_NODES * D;
    bf16* Qb  = (bf16*)d_ws;
    char* KVb = (char*)(Qb + ND);                    // N_NODES * 512 B (K/V interleaved)
    int* counts     = (int*)(KVb + (size_t)N_NODES * 512);
    int* offsets    = counts + N_NODES;
    int* rank       = offsets + N_NODES;             // N_EDGES ints
    int* csr_cols   = rank + N_EDGES;
    unsigned short* Wf = (unsigned short*)(csr_cols + N_EDGES);  // 3*32768 ushort
    int* gcur       = (int*)(Wf + 3 * 32768);

    prep_kernel<<<NB, 256, 0, stream>>>(qW, kW, vW, Wf, counts, gcur);
    qkv_mfma<<<NBQ, 256, 0, stream>>>(emb, Wf, Qb, KVb, rows, counts, rank);
    scan_one<<<NB, 256, 0, stream>>>(counts, offsets, gcur);
    scatter_kernel<<<(N_EDGES / 4 + 255) / 256, 256, 0, stream>>>(rows, cols, rank, offsets, csr_cols);
    fused_node<<<(N_NODES + 3) / 4, 256, 0, stream>>>(
        Qb, KVb, offsets, counts, csr_cols, emb, gamma, beta, out);
}

// Round 10
// 369.748 us; speedup vs baseline: 1.0002x; 1.0002x over previous
//
#include <hip/hip_runtime.h>
#include <hip/hip_bf16.h>

#define N_NODES 100000
#define N_EDGES 800000
#define D 128
#define NH 8
#define NB ((N_NODES + 255) / 256)   // 391 blocks (prep zero / scan_one)
#define NBQ ((N_NODES + 63) / 64)    // 1563 qkv blocks (64 rows each)

typedef __hip_bfloat16 bf16;
typedef __bf16 bf16x8 __attribute__((ext_vector_type(8)));
typedef float  f32x4  __attribute__((ext_vector_type(4)));

__device__ __forceinline__ unsigned short f2bu(float x) {
    bf16 b = __float2bfloat16(x);
    return *reinterpret_cast<unsigned short*>(&b);
}
__device__ __forceinline__ float bu2f(unsigned short u) {
    return __uint_as_float(((unsigned)u) << 16);
}
__device__ __forceinline__ float bfe0(unsigned u) { return __uint_as_float(u << 16); }
__device__ __forceinline__ float bfe1(unsigned u) { return __uint_as_float(u & 0xffff0000u); }

union frag_u { unsigned short u[8]; bf16x8 v; };

// DPP-based add of a lane-shuffled copy (VALU pipe; no DS traffic).
template<int CTRL>
__device__ __forceinline__ float dpp_add(float x) {
    int y = __builtin_amdgcn_mov_dpp(__float_as_int(x), CTRL, 0xf, 0xf, true);
    return x + __int_as_float(y);
}
// Sum over each aligned 8-lane group: xor1, xor2, xor7 spans the 3-bit group.
__device__ __forceinline__ float red8(float x) {
    x = dpp_add<0xB1>(x);    // quad_perm [1,0,3,2]  -> lane ^ 1
    x = dpp_add<0x4E>(x);    // quad_perm [2,3,0,1]  -> lane ^ 2
    x = dpp_add<0x141>(x);   // row_half_mirror      -> lane ^ 7
    return x;
}

// ---------------------------------------------------------------------------
// Kernel 0: lay W out in MFMA B-fragment order (hi/lo bf16 split), zero the
// per-node edge counters and the global scan cursor.
// Matrix 0 = Q.  Matrices 1,2 = KV-low/KV-high with columns permuted so the
// MFMA output row IS the fused dword-interleaved KV layout.
// ---------------------------------------------------------------------------
__global__ __launch_bounds__(256) void prep_kernel(
    const float* __restrict__ Wq, const float* __restrict__ Wk, const float* __restrict__ Wv,
    unsigned short* __restrict__ Wf, int* __restrict__ counts, int* __restrict__ gcur)
{
    int t = blockIdx.x * 256 + threadIdx.x;
    if (t < N_NODES) counts[t] = 0;
    if (t == 0) *gcur = 0;
    if (t < 3 * 32 * 64) {
        int lane = t & 63;
        int ct   = (t >> 6) & 31;
        int mat  = t >> 11;
        int c  = ct >> 3, tt = ct & 7;
        int n  = tt * 16 + (lane & 15);
        int kb = c * 32 + (lane >> 4) * 8;
        const float* W;
        int col;
        if (mat == 0) {
            W = Wq; col = n;
        } else {
            int g = (mat - 1) * 128 + n;
            W = (g & 2) ? Wv : Wk;
            col = ((g >> 2) << 1) | (g & 1);
        }
        unsigned short* dst = Wf + (size_t)mat * 32768 + (size_t)ct * 1024 + (size_t)lane * 8;
#pragma unroll
        for (int j = 0; j < 8; ++j) {
            float w  = W[(size_t)(kb + j) * D + col];
            unsigned short hb = f2bu(w);
            float lo = w - bu2f(hb);
            dst[j]       = hb;          // hi (part 0)
            dst[512 + j] = f2bu(lo);    // lo (part 1)
        }
    }
}

// ---------------------------------------------------------------------------
// Kernel 1: fused Q/KV projection via bf16 MFMA with hi/lo precision split.
// 64 rows/block, 16 rows/wave.  Edge histogram + rank capture fused into the
// prologue (makes scatter atomic-free).
// Register prefetch (issue-early/write-late) RETRY: round 9's version was
// invalidated by a VGPR spill — the allocator stayed at 64 VGPRs and spilled
// pre[8] to scratch (FETCH +77 MB / WRITE +266 MB of phantom traffic).
// __launch_bounds__(256, 4) raises the cap to 128 VGPRs (4 waves/EU) so
// pre[] lives in registers.  Everything else identical to round 9.
// ---------------------------------------------------------------------------
__global__ __launch_bounds__(256, 4) void qkv_mfma(
    const float* __restrict__ E, const unsigned short* __restrict__ Wf,
    bf16* __restrict__ Q, char* __restrict__ KVb,
    const int* __restrict__ rows, int* __restrict__ counts,
    int* __restrict__ rank)
{
    __shared__ unsigned short bsh[16384];   // 32 KB: B staging, then epilogue
    const int tid  = threadIdx.x;
    const int wave = tid >> 6;
    const int lane = tid & 63;
    const int r0w  = blockIdx.x * 64 + wave * 16;   // this wave's 16 rows

    // --- edge histogram + rank capture: 2 edges/thread ---
    {
        int e0 = (blockIdx.x * 256 + tid) * 2;
        if (e0 < N_EDGES) {
            int2 r2 = *reinterpret_cast<const int2*>(rows + e0);
            int2 rk;
            rk.x = atomicAdd(&counts[r2.x], 1);
            rk.y = atomicAdd(&counts[r2.y], 1);
            *reinterpret_cast<int2*>(rank + e0) = rk;
        }
    }

    // --- prefetch phase 0's 32 KB into registers (completes under A-load) ---
    uint4 pre[8];
    {
        const uint4* s0 = reinterpret_cast<const uint4*>(Wf);
#pragma unroll
        for (int k = 0; k < 8; ++k)
            pre[k] = s0[k * 256 + tid];
    }

    const int am = lane & 15;    // A row within 16-tile
    const int aq = lane >> 4;    // k quad

    // Load + split A fragments: 4 k-chunks x 8 bf16 (hi/lo).
    frag_u ahi[4], alo[4];
    {
        int row = r0w + am;
        if (row >= N_NODES) row = N_NODES - 1;     // clamp; stores are guarded
        const float* erow = E + (size_t)row * D + aq * 8;
#pragma unroll
        for (int c = 0; c < 4; ++c) {
            float4 e0 = *reinterpret_cast<const float4*>(erow + c * 32);
            float4 e1 = *reinterpret_cast<const float4*>(erow + c * 32 + 4);
            float ef[8] = {e0.x, e0.y, e0.z, e0.w, e1.x, e1.y, e1.z, e1.w};
#pragma unroll
            for (int j = 0; j < 8; ++j) {
                unsigned short hb = f2bu(ef[j]);
                ahi[c].u[j] = hb;
                alo[c].u[j] = f2bu(ef[j] - bu2f(hb));
            }
        }
    }

#pragma unroll
    for (int mat = 0; mat < 3; ++mat) {
        f32x4 acc[8];
#pragma unroll
        for (int t = 0; t < 8; ++t)
            acc[t] = (f32x4){0.f, 0.f, 0.f, 0.f};

#pragma unroll
        for (int half = 0; half < 2; ++half) {
            const int ph = mat * 2 + half;
            __syncthreads();    // previous users of bsh are done
            // write-late: commit the prefetched 32 KB to LDS
            {
                uint4* dstv = reinterpret_cast<uint4*>(bsh);
#pragma unroll
                for (int k = 0; k < 8; ++k)
                    dstv[k * 256 + tid] = pre[k];
            }
            // issue-early: kick off next phase's loads; they fly during MFMA
            if (ph < 5) {
                const uint4* sn = reinterpret_cast<const uint4*>(Wf + (size_t)(ph + 1) * 16384);
#pragma unroll
                for (int k = 0; k < 8; ++k)
                    pre[k] = sn[k * 256 + tid];
            }
            __syncthreads();

#pragma unroll
            for (int t = 0; t < 8; ++t) {
#pragma unroll
                for (int cc = 0; cc < 2; ++cc) {
                    const unsigned short* bp = bsh + (cc * 8 + t) * 1024 + lane * 8;
                    bf16x8 bhi = *reinterpret_cast<const bf16x8*>(bp);
                    bf16x8 blo = *reinterpret_cast<const bf16x8*>(bp + 512);
                    const int c = half * 2 + cc;
                    acc[t] = __builtin_amdgcn_mfma_f32_16x16x32_bf16(alo[c].v, bhi, acc[t], 0, 0, 0);
                    acc[t] = __builtin_amdgcn_mfma_f32_16x16x32_bf16(ahi[c].v, blo, acc[t], 0, 0, 0);
                    acc[t] = __builtin_amdgcn_mfma_f32_16x16x32_bf16(ahi[c].v, bhi, acc[t], 0, 0, 0);
                }
            }
        }
        __syncthreads();   // all waves done reading B; bsh reusable per-wave

        // Epilogue: C-frags -> per-wave LDS slice (stride 136) -> coalesced
        // dwordx4 stores.  C layout: col = t*16+am, row = aq*4+r.
        unsigned short* ob = bsh + wave * 2176;   // 16 rows x 136
#pragma unroll
        for (int t = 0; t < 8; ++t)
#pragma unroll
            for (int r = 0; r < 4; ++r)
                ob[(aq * 4 + r) * 136 + t * 16 + am] = f2bu(acc[t][r]);
        {
            const int row = lane >> 2, c4 = lane & 3;
            int grow = r0w + row;
            if (grow < N_NODES) {
                const uint4* srcb = reinterpret_cast<const uint4*>(ob + row * 136 + c4 * 32);
                uint4 d0 = srcb[0], d1 = srcb[1], d2 = srcb[2], d3 = srcb[3];
                uint4* dst;
                if (mat == 0)
                    dst = reinterpret_cast<uint4*>(Q + (size_t)grow * D + c4 * 32);
                else
                    dst = reinterpret_cast<uint4*>(KVb + ((size_t)grow << 9)
                                                   + (size_t)(mat - 1) * 256 + (size_t)c4 * 64);
                dst[0] = d0; dst[1] = d1; dst[2] = d2; dst[3] = d3;
            }
        }
    }
}

// ---------------------------------------------------------------------------
// One-pass order-free exclusive offsets: wave prefix sum over 64 counts +
// one atomicAdd per wave on a global cursor.
// ---------------------------------------------------------------------------
__global__ __launch_bounds__(256) void scan_one(
    const int* __restrict__ counts, int* __restrict__ offsets,
    int* __restrict__ gcur)
{
    int lane = threadIdx.x & 63;
    int n = blockIdx.x * 256 + threadIdx.x;
    int v = (n < N_NODES) ? counts[n] : 0;
    int s = v;
#pragma unroll
    for (int d = 1; d < 64; d <<= 1) {
        int t = __shfl_up(s, d, 64);
        if (lane >= d) s += t;
    }
    int tot = __shfl(s, 63, 64);
    int base = 0;
    if (lane == 0) base = atomicAdd(gcur, tot);
    base = __shfl(base, 0, 64);
    if (n < N_NODES) offsets[n] = base + s - v;
}

// ---------------------------------------------------------------------------
// Atomic-free scatter: position = offsets[row] + rank[e] (rank captured by
// qkv's histogram).  4 edges/thread via int4 loads; N_EDGES % 4 == 0.
// ---------------------------------------------------------------------------
__global__ __launch_bounds__(256) void scatter_kernel(
    const int* __restrict__ rows, const int* __restrict__ cols,
    const int* __restrict__ rank, const int* __restrict__ offsets,
    int* __restrict__ csr_cols)
{
    int e0 = (blockIdx.x * 256 + threadIdx.x) * 4;
    if (e0 >= N_EDGES) return;
    int4 r4 = *reinterpret_cast<const int4*>(rows + e0);
    int4 k4 = *reinterpret_cast<const int4*>(rank + e0);
    int4 c4 = *reinterpret_cast<const int4*>(cols + e0);
    csr_cols[offsets[r4.x] + k4.x] = c4.x;
    csr_cols[offsets[r4.y] + k4.y] = c4.y;
    csr_cols[offsets[r4.z] + k4.z] = c4.z;
    csr_cols[offsets[r4.w] + k4.w] = c4.w;
}

// ---------------------------------------------------------------------------
// Fused per-node attention + residual + LayerNorm. One wave per node.
// (unchanged — pinned at ~76 µs by the random-gather LLC/HBM traffic wall)
// ---------------------------------------------------------------------------
__device__ __forceinline__ void edge_body(
    const char* __restrict__ KVb, int off, unsigned lane8,
    float q0, float q1, float CLIP2,
    float& acc0, float& acc1, float& nrm)
{
    uint2 kv = *reinterpret_cast<const uint2*>(KVb + (unsigned)off + lane8);
    float p = q0 * bfe0(kv.x) + q1 * bfe1(kv.x);
    p = red8(p);
    float s = __builtin_amdgcn_exp2f(fminf(fmaxf(p, -CLIP2), CLIP2));
    nrm  += s;
    acc0 += s * bfe0(kv.y);
    acc1 += s * bfe1(kv.y);
}

__global__ __launch_bounds__(256) void fused_node(
    const bf16* __restrict__ Qb, const char* __restrict__ KVb,
    const int* __restrict__ offsets, const int* __restrict__ counts,
    const int* __restrict__ csr_cols,
    const float* __restrict__ emb,
    const float* __restrict__ gamma, const float* __restrict__ beta,
    float* __restrict__ out)
{
    int n = blockIdx.x * 4 + (threadIdx.x >> 6);     // grid covers exactly N_NODES
    int lane = threadIdx.x & 63;

    const float L2E   = 1.44269504f;
    const float CLIP2 = 14.4269504f;                 // 10 * log2(e)

    unsigned qu = *reinterpret_cast<const unsigned*>(Qb + (size_t)n * D + lane * 2);
    float q0 = bfe0(qu) * L2E, q1 = bfe1(qu) * L2E;

    int start = offsets[n];
    int cnt   = counts[n];
    unsigned lane8 = (unsigned)(lane << 3);

    float acc0a = 0.f, acc1a = 0.f, nrma = 0.f;
    float acc0b = 0.f, acc1b = 0.f, nrmb = 0.f;

    for (int base = 0; base < cnt; base += 64) {
        int m = cnt - base; if (m > 64) m = 64;
        int moff = (base + lane < cnt) ? (csr_cols[start + base + lane] << 9) : 0;
        int j = 0;
        for (; j + 7 < m; j += 8) {
            int o0 = __builtin_amdgcn_readlane(moff, j + 0);
            int o1 = __builtin_amdgcn_readlane(moff, j + 1);
            int o2 = __builtin_amdgcn_readlane(moff, j + 2);
            int o3 = __builtin_amdgcn_readlane(moff, j + 3);
            int o4 = __builtin_amdgcn_readlane(moff, j + 4);
            int o5 = __builtin_amdgcn_readlane(moff, j + 5);
            int o6 = __builtin_amdgcn_readlane(moff, j + 6);
            int o7 = __builtin_amdgcn_readlane(moff, j + 7);
            edge_body(KVb, o0, lane8, q0, q1, CLIP2, acc0a, acc1a, nrma);
            edge_body(KVb, o1, lane8, q0, q1, CLIP2, acc0b, acc1b, nrmb);
            edge_body(KVb, o2, lane8, q0, q1, CLIP2, acc0a, acc1a, nrma);
            edge_body(KVb, o3, lane8, q0, q1, CLIP2, acc0b, acc1b, nrmb);
            edge_body(KVb, o4, lane8, q0, q1, CLIP2, acc0a, acc1a, nrma);
            edge_body(KVb, o5, lane8, q0, q1, CLIP2, acc0b, acc1b, nrmb);
            edge_body(KVb, o6, lane8, q0, q1, CLIP2, acc0a, acc1a, nrma);
            edge_body(KVb, o7, lane8, q0, q1, CLIP2, acc0b, acc1b, nrmb);
        }
        for (; j + 3 < m; j += 4) {
            int o0 = __builtin_amdgcn_readlane(moff, j + 0);
            int o1 = __builtin_amdgcn_readlane(moff, j + 1);
            int o2 = __builtin_amdgcn_readlane(moff, j + 2);
            int o3 = __builtin_amdgcn_readlane(moff, j + 3);
            edge_body(KVb, o0, lane8, q0, q1, CLIP2, acc0a, acc1a, nrma);
            edge_body(KVb, o1, lane8, q0, q1, CLIP2, acc0b, acc1b, nrmb);
            edge_body(KVb, o2, lane8, q0, q1, CLIP2, acc0a, acc1a, nrma);
            edge_body(KVb, o3, lane8, q0, q1, CLIP2, acc0b, acc1b, nrmb);
        }
        for (; j < m; ++j) {
            int o0 = __builtin_amdgcn_readlane(moff, j);
            edge_body(KVb, o0, lane8, q0, q1, CLIP2, acc0a, acc1a, nrma);
        }
    }

    float nrm  = nrma + nrmb;
    float acc0 = acc0a + acc0b;
    float acc1 = acc1a + acc1b;

    float w = 1.f / (nrm + 1e-8f);
    float2 e2 = *reinterpret_cast<const float2*>(emb + (size_t)n * D + lane * 2);
    float x0 = acc0 * w + e2.x;
    float x1 = acc1 * w + e2.y;

    // single-pass LayerNorm: reduce sum and sumsq together
    float s1 = x0 + x1;
    float s2 = x0 * x0 + x1 * x1;
#pragma unroll
    for (int off = 32; off; off >>= 1) {
        s1 += __shfl_xor(s1, off, 64);
        s2 += __shfl_xor(s2, off, 64);
    }
    float mean = s1 * (1.0f / 128.0f);
    float var  = fmaxf(s2 * (1.0f / 128.0f) - mean * mean, 0.f);
    float rs = rsqrtf(var + 1e-6f);

    float d0 = x0 - mean, d1 = x1 - mean;
    float2 g2 = *reinterpret_cast<const float2*>(gamma + lane * 2);
    float2 b2 = *reinterpret_cast<const float2*>(beta + lane * 2);
    float2 o2 = make_float2(d0 * rs * g2.x + b2.x, d1 * rs * g2.y + b2.y);
    *reinterpret_cast<float2*>(out + (size_t)n * D + lane * 2) = o2;
}

// ---------------------------------------------------------------------------
extern "C" void kernel_launch(void* const* d_in, const int* in_sizes, int n_in,
                              void* d_out, int out_size, void* d_ws, size_t ws_size,
                              hipStream_t stream)
{
    const float* emb   = (const float*)d_in[0];
    const float* qW    = (const float*)d_in[1];
    const float* kW    = (const float*)d_in[2];
    const float* vW    = (const float*)d_in[3];
    const float* gamma = (const float*)d_in[4];
    const float* beta  = (const float*)d_in[5];
    const int*   eidx  = (const int*)d_in[6];
    const int*   rows  = eidx;
    const int*   cols  = eidx + N_EDGES;
    float* out = (float*)d_out;

    const size_t ND = (size_t)N_NODES * D;
    bf16* Qb  = (bf16*)d_ws;
    char* KVb = (char*)(Qb + ND);                    // N_NODES * 512 B (K/V interleaved)
    int* counts     = (int*)(KVb + (size_t)N_NODES * 512);
    int* offsets    = counts + N_NODES;
    int* rank       = offsets + N_NODES;             // N_EDGES ints
    int* csr_cols   = rank + N_EDGES;
    unsigned short* Wf = (unsigned short*)(csr_cols + N_EDGES);  // 3*32768 ushort
    int* gcur       = (int*)(Wf + 3 * 32768);

    prep_kernel<<<NB, 256, 0, stream>>>(qW, kW, vW, Wf, counts, gcur);
    qkv_mfma<<<NBQ, 256, 0, stream>>>(emb, Wf, Qb, KVb, rows, counts, rank);
    scan_one<<<NB, 256, 0, stream>>>(counts, offsets, gcur);
    scatter_kernel<<<(N_EDGES / 4 + 255) / 256, 256, 0, stream>>>(rows, cols, rank, offsets, csr_cols);
    fused_node<<<(N_NODES + 3) / 4, 256, 0, stream>>>(
        Qb, KVb, offsets, counts, csr_cols, emb, gamma, beta, out);
}

// Round 11
// 291.398 us; speedup vs baseline: 1.2692x; 1.2689x over previous
//
#include <hip/hip_runtime.h>
#include <hip/hip_bf16.h>

#define N_NODES 100000
#define N_EDGES 800000
#define D 128
#define NH 8
#define NB ((N_NODES + 255) / 256)   // 391 blocks (prep zero / scan_one)
#define NBQ ((N_NODES + 63) / 64)    // 1563 qkv blocks (64 rows each)

typedef __hip_bfloat16 bf16;
typedef __bf16 bf16x8 __attribute__((ext_vector_type(8)));
typedef float  f32x4  __attribute__((ext_vector_type(4)));

__device__ __forceinline__ unsigned short f2bu(float x) {
    bf16 b = __float2bfloat16(x);
    return *reinterpret_cast<unsigned short*>(&b);
}
__device__ __forceinline__ float bu2f(unsigned short u) {
    return __uint_as_float(((unsigned)u) << 16);
}
__device__ __forceinline__ float bfe0(unsigned u) { return __uint_as_float(u << 16); }
__device__ __forceinline__ float bfe1(unsigned u) { return __uint_as_float(u & 0xffff0000u); }

union frag_u { unsigned short u[8]; bf16x8 v; };

// DPP-based add of a lane-shuffled copy (VALU pipe; no DS traffic).
template<int CTRL>
__device__ __forceinline__ float dpp_add(float x) {
    int y = __builtin_amdgcn_mov_dpp(__float_as_int(x), CTRL, 0xf, 0xf, true);
    return x + __int_as_float(y);
}
// Sum over each aligned 8-lane group: xor1, xor2, xor7 spans the 3-bit group.
__device__ __forceinline__ float red8(float x) {
    x = dpp_add<0xB1>(x);    // quad_perm [1,0,3,2]  -> lane ^ 1
    x = dpp_add<0x4E>(x);    // quad_perm [2,3,0,1]  -> lane ^ 2
    x = dpp_add<0x141>(x);   // row_half_mirror      -> lane ^ 7
    return x;
}

// ---------------------------------------------------------------------------
// Kernel 0: lay W out in MFMA B-fragment order (hi/lo bf16 split), zero the
// per-node edge counters and the global scan cursor.
// Matrix 0 = Q.  Matrices 1,2 = KV-low/KV-high with columns permuted so the
// MFMA output row IS the fused dword-interleaved KV layout.
// ---------------------------------------------------------------------------
__global__ __launch_bounds__(256) void prep_kernel(
    const float* __restrict__ Wq, const float* __restrict__ Wk, const float* __restrict__ Wv,
    unsigned short* __restrict__ Wf, int* __restrict__ counts, int* __restrict__ gcur)
{
    int t = blockIdx.x * 256 + threadIdx.x;
    if (t < N_NODES) counts[t] = 0;
    if (t == 0) *gcur = 0;
    if (t < 3 * 32 * 64) {
        int lane = t & 63;
        int ct   = (t >> 6) & 31;
        int mat  = t >> 11;
        int c  = ct >> 3, tt = ct & 7;
        int n  = tt * 16 + (lane & 15);
        int kb = c * 32 + (lane >> 4) * 8;
        const float* W;
        int col;
        if (mat == 0) {
            W = Wq; col = n;
        } else {
            int g = (mat - 1) * 128 + n;
            W = (g & 2) ? Wv : Wk;
            col = ((g >> 2) << 1) | (g & 1);
        }
        unsigned short* dst = Wf + (size_t)mat * 32768 + (size_t)ct * 1024 + (size_t)lane * 8;
#pragma unroll
        for (int j = 0; j < 8; ++j) {
            float w  = W[(size_t)(kb + j) * D + col];
            unsigned short hb = f2bu(w);
            float lo = w - bu2f(hb);
            dst[j]       = hb;          // hi (part 0)
            dst[512 + j] = f2bu(lo);    // lo (part 1)
        }
    }
}

// ---------------------------------------------------------------------------
// Kernel 1: fused Q/KV projection via bf16 MFMA with hi/lo precision split.
// THIS ROUND: no LDS staging at all — B-fragments are read DIRECTLY from
// global (Wf is 192 KB, chip-wide shared -> L1/L2-resident; each fragment
// read is a fully-coalesced 1 KB/wave dwordx4).  This deletes the 6
// {load -> vmcnt(0) -> barrier -> MFMA} phases whose exposed L2 latency was
// the 83-us structure (register-prefetch alternative spilled: r9/r10).
// The kernel is now BARRIER-FREE: the epilogue LDS slice is wave-private.
// LDS 32 KB -> 17 KB; 8 blocks/CU.  Per-acc accumulation order (c=0..3 per
// t) is unchanged -> bitwise-identical output.
// ---------------------------------------------------------------------------
__global__ __launch_bounds__(256) void qkv_mfma(
    const float* __restrict__ E, const unsigned short* __restrict__ Wf,
    bf16* __restrict__ Q, char* __restrict__ KVb,
    const int* __restrict__ rows, int* __restrict__ counts,
    int* __restrict__ rank)
{
    __shared__ unsigned short bsh[8704];    // 17 KB: wave-private epilogue slices
    const int tid  = threadIdx.x;
    const int wave = tid >> 6;
    const int lane = tid & 63;
    const int r0w  = blockIdx.x * 64 + wave * 16;   // this wave's 16 rows

    // --- edge histogram + rank capture: 2 edges/thread ---
    {
        int e0 = (blockIdx.x * 256 + tid) * 2;
        if (e0 < N_EDGES) {
            int2 r2 = *reinterpret_cast<const int2*>(rows + e0);
            int2 rk;
            rk.x = atomicAdd(&counts[r2.x], 1);
            rk.y = atomicAdd(&counts[r2.y], 1);
            *reinterpret_cast<int2*>(rank + e0) = rk;
        }
    }

    const int am = lane & 15;    // A row within 16-tile
    const int aq = lane >> 4;    // k quad

    // Load + split A fragments: 4 k-chunks x 8 bf16 (hi/lo).
    frag_u ahi[4], alo[4];
    {
        int row = r0w + am;
        if (row >= N_NODES) row = N_NODES - 1;     // clamp; stores are guarded
        const float* erow = E + (size_t)row * D + aq * 8;
#pragma unroll
        for (int c = 0; c < 4; ++c) {
            float4 e0 = *reinterpret_cast<const float4*>(erow + c * 32);
            float4 e1 = *reinterpret_cast<const float4*>(erow + c * 32 + 4);
            float ef[8] = {e0.x, e0.y, e0.z, e0.w, e1.x, e1.y, e1.z, e1.w};
#pragma unroll
            for (int j = 0; j < 8; ++j) {
                unsigned short hb = f2bu(ef[j]);
                ahi[c].u[j] = hb;
                alo[c].u[j] = f2bu(ef[j] - bu2f(hb));
            }
        }
    }

#pragma unroll
    for (int mat = 0; mat < 3; ++mat) {
        f32x4 acc[8];
#pragma unroll
        for (int t = 0; t < 8; ++t)
            acc[t] = (f32x4){0.f, 0.f, 0.f, 0.f};

        // B-fragment base for this lane: tile ctg = (c>>1)*16 + (c&1)*8 + t,
        // address = wm + ctg*1024 + lane*8 (hi), +512 (lo).  1 KB/wave
        // coalesced reads, L1/L2-resident.
        const unsigned short* wm = Wf + (size_t)mat * 32768 + (size_t)lane * 8;

#pragma unroll
        for (int t = 0; t < 8; ++t) {
#pragma unroll
            for (int c = 0; c < 4; ++c) {
                const unsigned short* bp = wm + (size_t)(((c >> 1) * 16 + (c & 1) * 8 + t)) * 1024;
                bf16x8 bhi = *reinterpret_cast<const bf16x8*>(bp);
                bf16x8 blo = *reinterpret_cast<const bf16x8*>(bp + 512);
                acc[t] = __builtin_amdgcn_mfma_f32_16x16x32_bf16(alo[c].v, bhi, acc[t], 0, 0, 0);
                acc[t] = __builtin_amdgcn_mfma_f32_16x16x32_bf16(ahi[c].v, blo, acc[t], 0, 0, 0);
                acc[t] = __builtin_amdgcn_mfma_f32_16x16x32_bf16(ahi[c].v, bhi, acc[t], 0, 0, 0);
            }
        }

        // Epilogue: C-frags -> per-wave LDS slice (stride 136) -> coalesced
        // dwordx4 stores.  C layout: col = t*16+am, row = aq*4+r.
        // Slice is wave-private: no __syncthreads needed (lgkmcnt only).
        unsigned short* ob = bsh + wave * 2176;   // 16 rows x 136
#pragma unroll
        for (int t = 0; t < 8; ++t)
#pragma unroll
            for (int r = 0; r < 4; ++r)
                ob[(aq * 4 + r) * 136 + t * 16 + am] = f2bu(acc[t][r]);
        {
            const int row = lane >> 2, c4 = lane & 3;
            int grow = r0w + row;
            if (grow < N_NODES) {
                const uint4* srcb = reinterpret_cast<const uint4*>(ob + row * 136 + c4 * 32);
                uint4 d0 = srcb[0], d1 = srcb[1], d2 = srcb[2], d3 = srcb[3];
                uint4* dst;
                if (mat == 0)
                    dst = reinterpret_cast<uint4*>(Q + (size_t)grow * D + c4 * 32);
                else
                    dst = reinterpret_cast<uint4*>(KVb + ((size_t)grow << 9)
                                                   + (size_t)(mat - 1) * 256 + (size_t)c4 * 64);
                dst[0] = d0; dst[1] = d1; dst[2] = d2; dst[3] = d3;
            }
        }
    }
}

// ---------------------------------------------------------------------------
// One-pass order-free exclusive offsets: wave prefix sum over 64 counts +
// one atomicAdd per wave on a global cursor.
// ---------------------------------------------------------------------------
__global__ __launch_bounds__(256) void scan_one(
    const int* __restrict__ counts, int* __restrict__ offsets,
    int* __restrict__ gcur)
{
    int lane = threadIdx.x & 63;
    int n = blockIdx.x * 256 + threadIdx.x;
    int v = (n < N_NODES) ? counts[n] : 0;
    int s = v;
#pragma unroll
    for (int d = 1; d < 64; d <<= 1) {
        int t = __shfl_up(s, d, 64);
        if (lane >= d) s += t;
    }
    int tot = __shfl(s, 63, 64);
    int base = 0;
    if (lane == 0) base = atomicAdd(gcur, tot);
    base = __shfl(base, 0, 64);
    if (n < N_NODES) offsets[n] = base + s - v;
}

// ---------------------------------------------------------------------------
// Atomic-free scatter: position = offsets[row] + rank[e] (rank captured by
// qkv's histogram).  4 edges/thread via int4 loads; N_EDGES % 4 == 0.
// ---------------------------------------------------------------------------
__global__ __launch_bounds__(256) void scatter_kernel(
    const int* __restrict__ rows, const int* __restrict__ cols,
    const int* __restrict__ rank, const int* __restrict__ offsets,
    int* __restrict__ csr_cols)
{
    int e0 = (blockIdx.x * 256 + threadIdx.x) * 4;
    if (e0 >= N_EDGES) return;
    int4 r4 = *reinterpret_cast<const int4*>(rows + e0);
    int4 k4 = *reinterpret_cast<const int4*>(rank + e0);
    int4 c4 = *reinterpret_cast<const int4*>(cols + e0);
    csr_cols[offsets[r4.x] + k4.x] = c4.x;
    csr_cols[offsets[r4.y] + k4.y] = c4.y;
    csr_cols[offsets[r4.z] + k4.z] = c4.z;
    csr_cols[offsets[r4.w] + k4.w] = c4.w;
}

// ---------------------------------------------------------------------------
// Fused per-node attention + residual + LayerNorm. One wave per node.
// (unchanged — pinned at ~76 µs by the random-gather LLC/HBM traffic wall)
// ---------------------------------------------------------------------------
__device__ __forceinline__ void edge_body(
    const char* __restrict__ KVb, int off, unsigned lane8,
    float q0, float q1, float CLIP2,
    float& acc0, float& acc1, float& nrm)
{
    uint2 kv = *reinterpret_cast<const uint2*>(KVb + (unsigned)off + lane8);
    float p = q0 * bfe0(kv.x) + q1 * bfe1(kv.x);
    p = red8(p);
    float s = __builtin_amdgcn_exp2f(fminf(fmaxf(p, -CLIP2), CLIP2));
    nrm  += s;
    acc0 += s * bfe0(kv.y);
    acc1 += s * bfe1(kv.y);
}

__global__ __launch_bounds__(256) void fused_node(
    const bf16* __restrict__ Qb, const char* __restrict__ KVb,
    const int* __restrict__ offsets, const int* __restrict__ counts,
    const int* __restrict__ csr_cols,
    const float* __restrict__ emb,
    const float* __restrict__ gamma, const float* __restrict__ beta,
    float* __restrict__ out)
{
    int n = blockIdx.x * 4 + (threadIdx.x >> 6);     // grid covers exactly N_NODES
    int lane = threadIdx.x & 63;

    const float L2E   = 1.44269504f;
    const float CLIP2 = 14.4269504f;                 // 10 * log2(e)

    unsigned qu = *reinterpret_cast<const unsigned*>(Qb + (size_t)n * D + lane * 2);
    float q0 = bfe0(qu) * L2E, q1 = bfe1(qu) * L2E;

    int start = offsets[n];
    int cnt   = counts[n];
    unsigned lane8 = (unsigned)(lane << 3);

    float acc0a = 0.f, acc1a = 0.f, nrma = 0.f;
    float acc0b = 0.f, acc1b = 0.f, nrmb = 0.f;

    for (int base = 0; base < cnt; base += 64) {
        int m = cnt - base; if (m > 64) m = 64;
        int moff = (base + lane < cnt) ? (csr_cols[start + base + lane] << 9) : 0;
        int j = 0;
        for (; j + 7 < m; j += 8) {
            int o0 = __builtin_amdgcn_readlane(moff, j + 0);
            int o1 = __builtin_amdgcn_readlane(moff, j + 1);
            int o2 = __builtin_amdgcn_readlane(moff, j + 2);
            int o3 = __builtin_amdgcn_readlane(moff, j + 3);
            int o4 = __builtin_amdgcn_readlane(moff, j + 4);
            int o5 = __builtin_amdgcn_readlane(moff, j + 5);
            int o6 = __builtin_amdgcn_readlane(moff, j + 6);
            int o7 = __builtin_amdgcn_readlane(moff, j + 7);
            edge_body(KVb, o0, lane8, q0, q1, CLIP2, acc0a, acc1a, nrma);
            edge_body(KVb, o1, lane8, q0, q1, CLIP2, acc0b, acc1b, nrmb);
            edge_body(KVb, o2, lane8, q0, q1, CLIP2, acc0a, acc1a, nrma);
            edge_body(KVb, o3, lane8, q0, q1, CLIP2, acc0b, acc1b, nrmb);
            edge_body(KVb, o4, lane8, q0, q1, CLIP2, acc0a, acc1a, nrma);
            edge_body(KVb, o5, lane8, q0, q1, CLIP2, acc0b, acc1b, nrmb);
            edge_body(KVb, o6, lane8, q0, q1, CLIP2, acc0a, acc1a, nrma);
            edge_body(KVb, o7, lane8, q0, q1, CLIP2, acc0b, acc1b, nrmb);
        }
        for (; j + 3 < m; j += 4) {
            int o0 = __builtin_amdgcn_readlane(moff, j + 0);
            int o1 = __builtin_amdgcn_readlane(moff, j + 1);
            int o2 = __builtin_amdgcn_readlane(moff, j + 2);
            int o3 = __builtin_amdgcn_readlane(moff, j + 3);
            edge_body(KVb, o0, lane8, q0, q1, CLIP2, acc0a, acc1a, nrma);
            edge_body(KVb, o1, lane8, q0, q1, CLIP2, acc0b, acc1b, nrmb);
            edge_body(KVb, o2, lane8, q0, q1, CLIP2, acc0a, acc1a, nrma);
            edge_body(KVb, o3, lane8, q0, q1, CLIP2, acc0b, acc1b, nrmb);
        }
        for (; j < m; ++j) {
            int o0 = __builtin_amdgcn_readlane(moff, j);
            edge_body(KVb, o0, lane8, q0, q1, CLIP2, acc0a, acc1a, nrma);
        }
    }

    float nrm  = nrma + nrmb;
    float acc0 = acc0a + acc0b;
    float acc1 = acc1a + acc1b;

    float w = 1.f / (nrm + 1e-8f);
    float2 e2 = *reinterpret_cast<const float2*>(emb + (size_t)n * D + lane * 2);
    float x0 = acc0 * w + e2.x;
    float x1 = acc1 * w + e2.y;

    // single-pass LayerNorm: reduce sum and sumsq together
    float s1 = x0 + x1;
    float s2 = x0 * x0 + x1 * x1;
#pragma unroll
    for (int off = 32; off; off >>= 1) {
        s1 += __shfl_xor(s1, off, 64);
        s2 += __shfl_xor(s2, off, 64);
    }
    float mean = s1 * (1.0f / 128.0f);
    float var  = fmaxf(s2 * (1.0f / 128.0f) - mean * mean, 0.f);
    float rs = rsqrtf(var + 1e-6f);

    float d0 = x0 - mean, d1 = x1 - mean;
    float2 g2 = *reinterpret_cast<const float2*>(gamma + lane * 2);
    float2 b2 = *reinterpret_cast<const float2*>(beta + lane * 2);
    float2 o2 = make_float2(d0 * rs * g2.x + b2.x, d1 * rs * g2.y + b2.y);
    *reinterpret_cast<float2*>(out + (size_t)n * D + lane * 2) = o2;
}

// ---------------------------------------------------------------------------
extern "C" void kernel_launch(void* const* d_in, const int* in_sizes, int n_in,
                              void* d_out, int out_size, void* d_ws, size_t ws_size,
                              hipStream_t stream)
{
    const float* emb   = (const float*)d_in[0];
    const float* qW    = (const float*)d_in[1];
    const float* kW    = (const float*)d_in[2];
    const float* vW    = (const float*)d_in[3];
    const float* gamma = (const float*)d_in[4];
    const float* beta  = (const float*)d_in[5];
    const int*   eidx  = (const int*)d_in[6];
    const int*   rows  = eidx;
    const int*   cols  = eidx + N_EDGES;
    float* out = (float*)d_out;

    const size_t ND = (size_t)N_NODES * D;
    bf16* Qb  = (bf16*)d_ws;
    char* KVb = (char*)(Qb + ND);                    // N_NODES * 512 B (K/V interleaved)
    int* counts     = (int*)(KVb + (size_t)N_NODES * 512);
    int* offsets    = counts + N_NODES;
    int* rank       = offsets + N_NODES;             // N_EDGES ints
    int* csr_cols   = rank + N_EDGES;
    unsigned short* Wf = (unsigned short*)(csr_cols + N_EDGES);  // 3*32768 ushort
    int* gcur       = (int*)(Wf + 3 * 32768);

    prep_kernel<<<NB, 256, 0, stream>>>(qW, kW, vW, Wf, counts, gcur);
    qkv_mfma<<<NBQ, 256, 0, stream>>>(emb, Wf, Qb, KVb, rows, counts, rank);
    scan_one<<<NB, 256, 0, stream>>>(counts, offsets, gcur);
    scatter_kernel<<<(N_EDGES / 4 + 255) / 256, 256, 0, stream>>>(rows, cols, rank, offsets, csr_cols);
    fused_node<<<(N_NODES + 3) / 4, 256, 0, stream>>>(
        Qb, KVb, offsets, counts, csr_cols, emb, gamma, beta, out);
}

// Round 12
// 270.525 us; speedup vs baseline: 1.3671x; 1.0772x over previous
//
#include <hip/hip_runtime.h>
#include <hip/hip_bf16.h>

#define N_NODES 100000
#define N_EDGES 800000
#define D 128
#define NH 8
#define NB ((N_NODES + 255) / 256)   // 391 blocks (prep zero / scan_one)
#define NBQ ((N_NODES + 63) / 64)    // 1563 row-blocks (64 rows each)

typedef __hip_bfloat16 bf16;
typedef __bf16 bf16x8 __attribute__((ext_vector_type(8)));
typedef float  f32x4  __attribute__((ext_vector_type(4)));

__device__ __forceinline__ unsigned short f2bu(float x) {
    bf16 b = __float2bfloat16(x);
    return *reinterpret_cast<unsigned short*>(&b);
}
__device__ __forceinline__ float bu2f(unsigned short u) {
    return __uint_as_float(((unsigned)u) << 16);
}
__device__ __forceinline__ float bfe0(unsigned u) { return __uint_as_float(u << 16); }
__device__ __forceinline__ float bfe1(unsigned u) { return __uint_as_float(u & 0xffff0000u); }

union frag_u { unsigned short u[8]; bf16x8 v; };

// DPP-based add of a lane-shuffled copy (VALU pipe; no DS traffic).
template<int CTRL>
__device__ __forceinline__ float dpp_add(float x) {
    int y = __builtin_amdgcn_mov_dpp(__float_as_int(x), CTRL, 0xf, 0xf, true);
    return x + __int_as_float(y);
}
// Sum over each aligned 8-lane group: xor1, xor2, xor7 spans the 3-bit group.
__device__ __forceinline__ float red8(float x) {
    x = dpp_add<0xB1>(x);    // quad_perm [1,0,3,2]  -> lane ^ 1
    x = dpp_add<0x4E>(x);    // quad_perm [2,3,0,1]  -> lane ^ 2
    x = dpp_add<0x141>(x);   // row_half_mirror      -> lane ^ 7
    return x;
}

// ---------------------------------------------------------------------------
// Kernel 0: lay W out in MFMA B-fragment order (hi/lo bf16 split), zero the
// per-node edge counters and the global scan cursor.
// Matrix 0 = Q.  Matrices 1,2 = KV-low/KV-high with columns permuted so the
// MFMA output row IS the fused dword-interleaved KV layout.
// ---------------------------------------------------------------------------
__global__ __launch_bounds__(256) void prep_kernel(
    const float* __restrict__ Wq, const float* __restrict__ Wk, const float* __restrict__ Wv,
    unsigned short* __restrict__ Wf, int* __restrict__ counts, int* __restrict__ gcur)
{
    int t = blockIdx.x * 256 + threadIdx.x;
    if (t < N_NODES) counts[t] = 0;
    if (t == 0) *gcur = 0;
    if (t < 3 * 32 * 64) {
        int lane = t & 63;
        int ct   = (t >> 6) & 31;
        int mat  = t >> 11;
        int c  = ct >> 3, tt = ct & 7;
        int n  = tt * 16 + (lane & 15);
        int kb = c * 32 + (lane >> 4) * 8;
        const float* W;
        int col;
        if (mat == 0) {
            W = Wq; col = n;
        } else {
            int g = (mat - 1) * 128 + n;
            W = (g & 2) ? Wv : Wk;
            col = ((g >> 2) << 1) | (g & 1);
        }
        unsigned short* dst = Wf + (size_t)mat * 32768 + (size_t)ct * 1024 + (size_t)lane * 8;
#pragma unroll
        for (int j = 0; j < 8; ++j) {
            float w  = W[(size_t)(kb + j) * D + col];
            unsigned short hb = f2bu(w);
            float lo = w - bu2f(hb);
            dst[j]       = hb;          // hi (part 0)
            dst[512 + j] = f2bu(lo);    // lo (part 1)
        }
    }
}

// ---------------------------------------------------------------------------
// Kernel 1: fused Q/KV projection via bf16 MFMA with hi/lo precision split.
// THIS ROUND: mat-split grid — 3x blocks, each block computes ONE matrix
// (mat = blockIdx.x % 3) for 64 rows (rowblk = blockIdx.x / 3).  Per-block
// serial path drops from 6 staging phases to 2; 4689 blocks (~18/CU queued,
// 5 resident on 32 KB LDS) keep the CU fed behind staging stalls.  Staging
// is the proven round-8 uint4 VGPR copy.  Accumulation order per acc[t]
// (c = 0..3) unchanged -> bitwise-identical output.  E rows are A-loaded 3x
// (L3-served, time-cheap).  Histogram + rank capture: 1 edge/thread on the
// 1.2M-thread grid (hides under MFMA; makes scatter atomic-free).
// ---------------------------------------------------------------------------
__global__ __launch_bounds__(256) void qkv_mfma(
    const float* __restrict__ E, const unsigned short* __restrict__ Wf,
    bf16* __restrict__ Q, char* __restrict__ KVb,
    const int* __restrict__ rows, int* __restrict__ counts,
    int* __restrict__ rank)
{
    __shared__ unsigned short bsh[16384];   // 32 KB: B staging, then epilogue
    const int tid  = threadIdx.x;
    const int wave = tid >> 6;
    const int lane = tid & 63;
    const int mat    = blockIdx.x % 3;
    const int rowblk = blockIdx.x / 3;
    const int r0w  = rowblk * 64 + wave * 16;   // this wave's 16 rows

    // --- edge histogram + rank capture: 1 edge/thread, 4689*256 >= 800000 ---
    {
        int e0 = blockIdx.x * 256 + tid;
        if (e0 < N_EDGES)
            rank[e0] = atomicAdd(&counts[rows[e0]], 1);
    }

    const int am = lane & 15;    // A row within 16-tile
    const int aq = lane >> 4;    // k quad

    // Load + split A fragments: 4 k-chunks x 8 bf16 (hi/lo).
    frag_u ahi[4], alo[4];
    {
        int row = r0w + am;
        if (row >= N_NODES) row = N_NODES - 1;     // clamp; stores are guarded
        const float* erow = E + (size_t)row * D + aq * 8;
#pragma unroll
        for (int c = 0; c < 4; ++c) {
            float4 e0 = *reinterpret_cast<const float4*>(erow + c * 32);
            float4 e1 = *reinterpret_cast<const float4*>(erow + c * 32 + 4);
            float ef[8] = {e0.x, e0.y, e0.z, e0.w, e1.x, e1.y, e1.z, e1.w};
#pragma unroll
            for (int j = 0; j < 8; ++j) {
                unsigned short hb = f2bu(ef[j]);
                ahi[c].u[j] = hb;
                alo[c].u[j] = f2bu(ef[j] - bu2f(hb));
            }
        }
    }

    f32x4 acc[8];
#pragma unroll
    for (int t = 0; t < 8; ++t)
        acc[t] = (f32x4){0.f, 0.f, 0.f, 0.f};

    const unsigned short* wm = Wf + (size_t)mat * 32768;

#pragma unroll
    for (int half = 0; half < 2; ++half) {
        __syncthreads();    // previous users of bsh are done
        // Stage 32 KB (c = 2*half .. 2*half+1): 2048 uint4, 8 per thread.
        const uint4* src = reinterpret_cast<const uint4*>(wm + half * 16384);
        uint4* dstv = reinterpret_cast<uint4*>(bsh);
#pragma unroll
        for (int k = 0; k < 8; ++k)
            dstv[k * 256 + tid] = src[k * 256 + tid];
        __syncthreads();

#pragma unroll
        for (int t = 0; t < 8; ++t) {
#pragma unroll
            for (int cc = 0; cc < 2; ++cc) {
                const unsigned short* bp = bsh + (cc * 8 + t) * 1024 + lane * 8;
                bf16x8 bhi = *reinterpret_cast<const bf16x8*>(bp);
                bf16x8 blo = *reinterpret_cast<const bf16x8*>(bp + 512);
                const int c = half * 2 + cc;
                acc[t] = __builtin_amdgcn_mfma_f32_16x16x32_bf16(alo[c].v, bhi, acc[t], 0, 0, 0);
                acc[t] = __builtin_amdgcn_mfma_f32_16x16x32_bf16(ahi[c].v, blo, acc[t], 0, 0, 0);
                acc[t] = __builtin_amdgcn_mfma_f32_16x16x32_bf16(ahi[c].v, bhi, acc[t], 0, 0, 0);
            }
        }
    }
    __syncthreads();   // all waves done reading B; bsh reusable per-wave

    // Epilogue: C-frags -> per-wave LDS slice (stride 136) -> coalesced
    // dwordx4 stores.  C layout: col = t*16+am, row = aq*4+r.
    unsigned short* ob = bsh + wave * 2176;   // 16 rows x 136
#pragma unroll
    for (int t = 0; t < 8; ++t)
#pragma unroll
        for (int r = 0; r < 4; ++r)
            ob[(aq * 4 + r) * 136 + t * 16 + am] = f2bu(acc[t][r]);
    {
        const int row = lane >> 2, c4 = lane & 3;
        int grow = r0w + row;
        if (grow < N_NODES) {
            const uint4* srcb = reinterpret_cast<const uint4*>(ob + row * 136 + c4 * 32);
            uint4 d0 = srcb[0], d1 = srcb[1], d2 = srcb[2], d3 = srcb[3];
            uint4* dst;
            if (mat == 0)
                dst = reinterpret_cast<uint4*>(Q + (size_t)grow * D + c4 * 32);
            else
                dst = reinterpret_cast<uint4*>(KVb + ((size_t)grow << 9)
                                               + (size_t)(mat - 1) * 256 + (size_t)c4 * 64);
            dst[0] = d0; dst[1] = d1; dst[2] = d2; dst[3] = d3;
        }
    }
}

// ---------------------------------------------------------------------------
// One-pass order-free exclusive offsets: wave prefix sum over 64 counts +
// one atomicAdd per wave on a global cursor.
// ---------------------------------------------------------------------------
__global__ __launch_bounds__(256) void scan_one(
    const int* __restrict__ counts, int* __restrict__ offsets,
    int* __restrict__ gcur)
{
    int lane = threadIdx.x & 63;
    int n = blockIdx.x * 256 + threadIdx.x;
    int v = (n < N_NODES) ? counts[n] : 0;
    int s = v;
#pragma unroll
    for (int d = 1; d < 64; d <<= 1) {
        int t = __shfl_up(s, d, 64);
        if (lane >= d) s += t;
    }
    int tot = __shfl(s, 63, 64);
    int base = 0;
    if (lane == 0) base = atomicAdd(gcur, tot);
    base = __shfl(base, 0, 64);
    if (n < N_NODES) offsets[n] = base + s - v;
}

// ---------------------------------------------------------------------------
// Atomic-free scatter: position = offsets[row] + rank[e] (rank captured by
// qkv's histogram).  4 edges/thread via int4 loads; N_EDGES % 4 == 0.
// ---------------------------------------------------------------------------
__global__ __launch_bounds__(256) void scatter_kernel(
    const int* __restrict__ rows, const int* __restrict__ cols,
    const int* __restrict__ rank, const int* __restrict__ offsets,
    int* __restrict__ csr_cols)
{
    int e0 = (blockIdx.x * 256 + threadIdx.x) * 4;
    if (e0 >= N_EDGES) return;
    int4 r4 = *reinterpret_cast<const int4*>(rows + e0);
    int4 k4 = *reinterpret_cast<const int4*>(rank + e0);
    int4 c4 = *reinterpret_cast<const int4*>(cols + e0);
    csr_cols[offsets[r4.x] + k4.x] = c4.x;
    csr_cols[offsets[r4.y] + k4.y] = c4.y;
    csr_cols[offsets[r4.z] + k4.z] = c4.z;
    csr_cols[offsets[r4.w] + k4.w] = c4.w;
}

// ---------------------------------------------------------------------------
// Fused per-node attention + residual + LayerNorm. One wave per node.
// (unchanged — pinned at ~76 µs by the random-gather LLC/HBM traffic wall)
// ---------------------------------------------------------------------------
__device__ __forceinline__ void edge_body(
    const char* __restrict__ KVb, int off, unsigned lane8,
    float q0, float q1, float CLIP2,
    float& acc0, float& acc1, float& nrm)
{
    uint2 kv = *reinterpret_cast<const uint2*>(KVb + (unsigned)off + lane8);
    float p = q0 * bfe0(kv.x) + q1 * bfe1(kv.x);
    p = red8(p);
    float s = __builtin_amdgcn_exp2f(fminf(fmaxf(p, -CLIP2), CLIP2));
    nrm  += s;
    acc0 += s * bfe0(kv.y);
    acc1 += s * bfe1(kv.y);
}

__global__ __launch_bounds__(256) void fused_node(
    const bf16* __restrict__ Qb, const char* __restrict__ KVb,
    const int* __restrict__ offsets, const int* __restrict__ counts,
    const int* __restrict__ csr_cols,
    const float* __restrict__ emb,
    const float* __restrict__ gamma, const float* __restrict__ beta,
    float* __restrict__ out)
{
    int n = blockIdx.x * 4 + (threadIdx.x >> 6);     // grid covers exactly N_NODES
    int lane = threadIdx.x & 63;

    const float L2E   = 1.44269504f;
    const float CLIP2 = 14.4269504f;                 // 10 * log2(e)

    unsigned qu = *reinterpret_cast<const unsigned*>(Qb + (size_t)n * D + lane * 2);
    float q0 = bfe0(qu) * L2E, q1 = bfe1(qu) * L2E;

    int start = offsets[n];
    int cnt   = counts[n];
    unsigned lane8 = (unsigned)(lane << 3);

    float acc0a = 0.f, acc1a = 0.f, nrma = 0.f;
    float acc0b = 0.f, acc1b = 0.f, nrmb = 0.f;

    for (int base = 0; base < cnt; base += 64) {
        int m = cnt - base; if (m > 64) m = 64;
        int moff = (base + lane < cnt) ? (csr_cols[start + base + lane] << 9) : 0;
        int j = 0;
        for (; j + 7 < m; j += 8) {
            int o0 = __builtin_amdgcn_readlane(moff, j + 0);
            int o1 = __builtin_amdgcn_readlane(moff, j + 1);
            int o2 = __builtin_amdgcn_readlane(moff, j + 2);
            int o3 = __builtin_amdgcn_readlane(moff, j + 3);
            int o4 = __builtin_amdgcn_readlane(moff, j + 4);
            int o5 = __builtin_amdgcn_readlane(moff, j + 5);
            int o6 = __builtin_amdgcn_readlane(moff, j + 6);
            int o7 = __builtin_amdgcn_readlane(moff, j + 7);
            edge_body(KVb, o0, lane8, q0, q1, CLIP2, acc0a, acc1a, nrma);
            edge_body(KVb, o1, lane8, q0, q1, CLIP2, acc0b, acc1b, nrmb);
            edge_body(KVb, o2, lane8, q0, q1, CLIP2, acc0a, acc1a, nrma);
            edge_body(KVb, o3, lane8, q0, q1, CLIP2, acc0b, acc1b, nrmb);
            edge_body(KVb, o4, lane8, q0, q1, CLIP2, acc0a, acc1a, nrma);
            edge_body(KVb, o5, lane8, q0, q1, CLIP2, acc0b, acc1b, nrmb);
            edge_body(KVb, o6, lane8, q0, q1, CLIP2, acc0a, acc1a, nrma);
            edge_body(KVb, o7, lane8, q0, q1, CLIP2, acc0b, acc1b, nrmb);
        }
        for (; j + 3 < m; j += 4) {
            int o0 = __builtin_amdgcn_readlane(moff, j + 0);
            int o1 = __builtin_amdgcn_readlane(moff, j + 1);
            int o2 = __builtin_amdgcn_readlane(moff, j + 2);
            int o3 = __builtin_amdgcn_readlane(moff, j + 3);
            edge_body(KVb, o0, lane8, q0, q1, CLIP2, acc0a, acc1a, nrma);
            edge_body(KVb, o1, lane8, q0, q1, CLIP2, acc0b, acc1b, nrmb);
            edge_body(KVb, o2, lane8, q0, q1, CLIP2, acc0a, acc1a, nrma);
            edge_body(KVb, o3, lane8, q0, q1, CLIP2, acc0b, acc1b, nrmb);
        }
        for (; j < m; ++j) {
            int o0 = __builtin_amdgcn_readlane(moff, j);
            edge_body(KVb, o0, lane8, q0, q1, CLIP2, acc0a, acc1a, nrma);
        }
    }

    float nrm  = nrma + nrmb;
    float acc0 = acc0a + acc0b;
    float acc1 = acc1a + acc1b;

    float w = 1.f / (nrm + 1e-8f);
    float2 e2 = *reinterpret_cast<const float2*>(emb + (size_t)n * D + lane * 2);
    float x0 = acc0 * w + e2.x;
    float x1 = acc1 * w + e2.y;

    // single-pass LayerNorm: reduce sum and sumsq together
    float s1 = x0 + x1;
    float s2 = x0 * x0 + x1 * x1;
#pragma unroll
    for (int off = 32; off; off >>= 1) {
        s1 += __shfl_xor(s1, off, 64);
        s2 += __shfl_xor(s2, off, 64);
    }
    float mean = s1 * (1.0f / 128.0f);
    float var  = fmaxf(s2 * (1.0f / 128.0f) - mean * mean, 0.f);
    float rs = rsqrtf(var + 1e-6f);

    float d0 = x0 - mean, d1 = x1 - mean;
    float2 g2 = *reinterpret_cast<const float2*>(gamma + lane * 2);
    float2 b2 = *reinterpret_cast<const float2*>(beta + lane * 2);
    float2 o2 = make_float2(d0 * rs * g2.x + b2.x, d1 * rs * g2.y + b2.y);
    *reinterpret_cast<float2*>(out + (size_t)n * D + lane * 2) = o2;
}

// ---------------------------------------------------------------------------
extern "C" void kernel_launch(void* const* d_in, const int* in_sizes, int n_in,
                              void* d_out, int out_size, void* d_ws, size_t ws_size,
                              hipStream_t stream)
{
    const float* emb   = (const float*)d_in[0];
    const float* qW    = (const float*)d_in[1];
    const float* kW    = (const float*)d_in[2];
    const float* vW    = (const float*)d_in[3];
    const float* gamma = (const float*)d_in[4];
    const float* beta  = (const float*)d_in[5];
    const int*   eidx  = (const int*)d_in[6];
    const int*   rows  = eidx;
    const int*   cols  = eidx + N_EDGES;
    float* out = (float*)d_out;

    const size_t ND = (size_t)N_NODES * D;
    bf16* Qb  = (bf16*)d_ws;
    char* KVb = (char*)(Qb + ND);                    // N_NODES * 512 B (K/V interleaved)
    int* counts     = (int*)(KVb + (size_t)N_NODES * 512);
    int* offsets    = counts + N_NODES;
    int* rank       = offsets + N_NODES;             // N_EDGES ints
    int* csr_cols   = rank + N_EDGES;
    unsigned short* Wf = (unsigned short*)(csr_cols + N_EDGES);  // 3*32768 ushort
    int* gcur       = (int*)(Wf + 3 * 32768);

    prep_kernel<<<NB, 256, 0, stream>>>(qW, kW, vW, Wf, counts, gcur);
    qkv_mfma<<<3 * NBQ, 256, 0, stream>>>(emb, Wf, Qb, KVb, rows, counts, rank);
    scan_one<<<NB, 256, 0, stream>>>(counts, offsets, gcur);
    scatter_kernel<<<(N_EDGES / 4 + 255) / 256, 256, 0, stream>>>(rows, cols, rank, offsets, csr_cols);
    fused_node<<<(N_NODES + 3) / 4, 256, 0, stream>>>(
        Qb, KVb, offsets, counts, csr_cols, emb, gamma, beta, out);
}